// Round 1
// 738.546 us; speedup vs baseline: 1.3597x; 1.3597x over previous
//
#include <hip/hip_runtime.h>
#include <hip/hip_bf16.h>
#include <cstddef>

#define NF 13824
#define NM 512

typedef __attribute__((ext_vector_type(8))) short bf16x8;
typedef __attribute__((ext_vector_type(4))) float f32x4;

// ---------------- weight transpose: WT[ci][co] = W[co][ci] ----------------
__global__ void k_transpose(const float* __restrict__ W, float* __restrict__ WT, int Cout, int Cin){
  int idx = blockIdx.x*256 + threadIdx.x;
  if (idx >= Cout*Cin) return;
  int co = idx / Cin, ci = idx % Cin;
  WT[(size_t)ci*Cout + co] = W[idx];
}

// ---------------- per-row (b,c) mean/var over N ----------------
__global__ void k_stats(const float* __restrict__ in, float2* __restrict__ st, int N){
  int row = blockIdx.x;
  const float* p = in + (size_t)row*N;
  float s=0.f, q=0.f;
  for (int i=threadIdx.x; i<N; i+=256){ float v=p[i]; s+=v; q+=v*v; }
  __shared__ float rs[256], rq[256];
  rs[threadIdx.x]=s; rq[threadIdx.x]=q;
  __syncthreads();
  for (int o=128;o>0;o>>=1){
    if (threadIdx.x<o){ rs[threadIdx.x]+=rs[threadIdx.x+o]; rq[threadIdx.x]+=rq[threadIdx.x+o]; }
    __syncthreads();
  }
  if (threadIdx.x==0){
    float m = rs[0]/N;
    float v = rq[0]/N - m*m;
    st[row] = make_float2(m, v>0.f? v:0.f);
  }
}

// ---------------- stats (+ optional SE scale) -> affine (a,b) ----------------
__global__ void k_make_tf(const float2* __restrict__ st, const float* __restrict__ sbuf,
                          float2* __restrict__ tf, int rows){
  int i = blockIdx.x*256 + threadIdx.x;
  if (i>=rows) return;
  float s = sbuf ? sbuf[i] : 1.f;
  float2 mv = st[i];
  float a = s*rsqrtf(s*s*mv.y + 1e-5f);
  tf[i] = make_float2(a, -mv.x*a);
}

// ---------------- depthwise 3x3x3 conv on 24^3 via LDS-staged channel ----------------
// One block per (b,c). Whole channel staged into zero-haloed LDS volume
// [26 d][26 h][28 w-stride]; data voxel (d,h,w) at lds[4 + (d+1)*728 + (h+1)*28 + w].
// Slots 24..27 of every row stay zero, so row[-1] and row[24] are in-place w-halos.
__global__ __launch_bounds__(256) void k_dw3t(const float* __restrict__ in, const float* __restrict__ w,
                      const float2* __restrict__ tf, float* __restrict__ out,
                      int C, int relu){
  int bc = blockIdx.x;
  int c = bc % C;
  __shared__ float lds[4 + 26*728];          // 75728 B
  float a = 1.f, bb = 0.f;
  if (tf){ float2 t = tf[bc]; a=t.x; bb=t.y; }

  // zero entire buffer (halos rely on this)
  {
    float4* l4 = (float4*)lds;
    float4 z = make_float4(0.f,0.f,0.f,0.f);
    for (int i=threadIdx.x; i<(4+26*728)/4; i+=256) l4[i] = z;
  }
  __syncthreads();

  // fill interior with affine(+relu) applied; coalesced float4 global reads,
  // aligned conflict-free ds_write_b128 (lane stride = 16B)
  const float* pin = in + (size_t)bc*NF;
  for (int i=threadIdx.x; i<NF/4; i+=256){
    int n = i*4;
    int d = n/576, r2 = n%576;
    int h = r2/24, wq = r2%24;                // wq multiple of 4
    float4 v = *(const float4*)(pin + n);
    float v0 = a*v.x+bb, v1 = a*v.y+bb, v2 = a*v.z+bb, v3 = a*v.w+bb;
    if (relu){ v0=fmaxf(v0,0.f); v1=fmaxf(v1,0.f); v2=fmaxf(v2,0.f); v3=fmaxf(v3,0.f); }
    *(float4*)(lds + 4 + (d+1)*728 + (h+1)*28 + wq) = make_float4(v0,v1,v2,v3);
  }

  // weights (uniform per block -> scalar regs)
  const float* wc = w + c*27;
  float wr[27];
  #pragma unroll
  for (int k=0;k<27;k++) wr[k] = wc[k];
  __syncthreads();

  // each thread computes full 24-wide output rows; no boundary branches
  for (int r = threadIdx.x; r < 576; r += 256){
    int d = r/24, h = r%24;
    float acc[24];
    #pragma unroll
    for (int i=0;i<24;i++) acc[i] = 0.f;
    #pragma unroll
    for (int kd=0;kd<3;kd++){
      #pragma unroll
      for (int kh=0;kh<3;kh++){
        const float* row = lds + 4 + (d+kd)*728 + (h+kh)*28;
        float rr[24];
        #pragma unroll
        for (int q=0;q<6;q++){
          float4 v4 = *(const float4*)(row + 4*q);
          rr[4*q]=v4.x; rr[4*q+1]=v4.y; rr[4*q+2]=v4.z; rr[4*q+3]=v4.w;
        }
        float rl = row[-1];                   // left halo (zero slot of prev row)
        float rrgt = row[24];                 // right halo (zero slot)
        float w0 = wr[kd*9+kh*3+0], w1 = wr[kd*9+kh*3+1], w2 = wr[kd*9+kh*3+2];
        acc[0] += w0*rl + w1*rr[0] + w2*rr[1];
        #pragma unroll
        for (int i=1;i<23;i++) acc[i] += w0*rr[i-1] + w1*rr[i] + w2*rr[i+1];
        acc[23] += w0*rr[22] + w1*rr[23] + w2*rrgt;
      }
    }
    float* op = out + (size_t)bc*NF + r*24;
    #pragma unroll
    for (int q=0;q<6;q++)
      *(float4*)(op + 4*q) = make_float4(acc[4*q],acc[4*q+1],acc[4*q+2],acc[4*q+3]);
  }
}

// ---------------- pointwise conv as tiled SGEMM ----------------
// mode 0: plain f32 layout out0 (+ optional residual)
// mode 1: q (co<256) -> bf16 n-major qnm[bh][n][64]; v (co>=256) -> bf16 d-major vdm[bh][64][N]
__global__ __launch_bounds__(256) void k_pw(const float* __restrict__ in, const float* __restrict__ WT,
                    const float2* __restrict__ tf, int relu,
                    int Cin, int Cout, int N,
                    const float* __restrict__ res,
                    float* __restrict__ out0,
                    __hip_bfloat16* __restrict__ qnm, __hip_bfloat16* __restrict__ vdm,
                    int mode){
  int b = blockIdx.z;
  int n0 = blockIdx.x*64, co0 = blockIdx.y*64;
  int tx = threadIdx.x & 15, ty = threadIdx.x >> 4;
  __shared__ float wl[32][68];
  __shared__ float il[32][68];
  float acc[4][4] = {};
  const float* inb = in + (size_t)b*Cin*N;
  for (int c0=0;c0<Cin;c0+=32){
    __syncthreads();
    {
      int cc = threadIdx.x & 63, g = threadIdx.x >> 6;
      #pragma unroll
      for (int rr=0;rr<8;rr++){
        int ci = g + 4*rr;
        wl[ci][cc] = WT[(size_t)(c0+ci)*Cout + co0 + cc];
        float v = inb[(size_t)(c0+ci)*N + n0 + cc];
        if (tf){ float2 t = tf[b*Cin + c0 + ci]; v = t.x*v + t.y; }
        if (relu) v = fmaxf(v, 0.f);
        il[ci][cc] = v;
      }
    }
    __syncthreads();
    #pragma unroll
    for (int ci=0;ci<32;ci++){
      float4 a4 = *(const float4*)&wl[ci][ty*4];
      float4 b4 = *(const float4*)&il[ci][tx*4];
      acc[0][0]+=a4.x*b4.x; acc[0][1]+=a4.x*b4.y; acc[0][2]+=a4.x*b4.z; acc[0][3]+=a4.x*b4.w;
      acc[1][0]+=a4.y*b4.x; acc[1][1]+=a4.y*b4.y; acc[1][2]+=a4.y*b4.z; acc[1][3]+=a4.y*b4.w;
      acc[2][0]+=a4.z*b4.x; acc[2][1]+=a4.z*b4.y; acc[2][2]+=a4.z*b4.z; acc[2][3]+=a4.z*b4.w;
      acc[3][0]+=a4.w*b4.x; acc[3][1]+=a4.w*b4.y; acc[3][2]+=a4.w*b4.z; acc[3][3]+=a4.w*b4.w;
    }
  }
  if (mode==0){
    #pragma unroll
    for (int i=0;i<4;i++){
      int co = co0 + ty*4 + i;
      float* op = out0 + ((size_t)b*Cout + co)*N;
      #pragma unroll
      for (int j=0;j<4;j++){
        int n = n0 + tx*4 + j;
        float v = acc[i][j];
        if (res) v += res[((size_t)b*Cout + co)*N + n];
        op[n] = v;
      }
    }
  } else {
    // co0 multiple of 64; thread's 4 co are 4 heads at fixed d
    int ccbase = (co0 & 255) + ty*4;
    int dd = ccbase >> 2;
    bool isq = (co0 < 256);
    #pragma unroll
    for (int i=0;i<4;i++){
      int bhid = b*4 + i;   // head = i
      #pragma unroll
      for (int j=0;j<4;j++){
        int n = n0 + tx*4 + j;
        __hip_bfloat16 v = __float2bfloat16(acc[i][j]);
        if (isq) qnm[((size_t)bhid*N + n)*64 + dd] = v;
        else     vdm[((size_t)(bhid*64 + dd))*N + n] = v;
      }
    }
  }
}

// ---------------- feat-direction attention (MFMA, no-max softmax over 512 map tokens) ----
// qf: [8bh][NF][64] bf16 n-major ; qm: [8bh][512][64] bf16 n-major ; vm: [8bh][64][512] bf16 d-major
// fo: [b][c=d*4+h][NF] f32
__global__ __launch_bounds__(256) void k_fattn(const __hip_bfloat16* __restrict__ qf,
    const __hip_bfloat16* __restrict__ qm, const __hip_bfloat16* __restrict__ vm,
    float* __restrict__ fo){
  int bh = blockIdx.y, b = bh>>2, h = bh&3;
  int w = threadIdx.x>>6, l = threadIdx.x&63;
  int i0 = blockIdx.x*64 + w*16;
  int lr = l&15, lg = l>>4;
  __shared__ __hip_bfloat16 pl[4][16][40];
  __shared__ float rsl[4][16];
  const __hip_bfloat16* qb = qf + ((size_t)bh*NF + i0 + lr)*64 + lg*8;
  bf16x8 aq0 = *(const bf16x8*)(qb);
  bf16x8 aq1 = *(const bf16x8*)(qb + 32);
  f32x4 facc[4];
  #pragma unroll
  for (int t=0;t<4;t++){ facc[t][0]=0.f; facc[t][1]=0.f; facc[t][2]=0.f; facc[t][3]=0.f; }
  float rs[4] = {0.f,0.f,0.f,0.f};
  for (int jt=0; jt<16; jt++){
    int j0 = jt*32;
    const __hip_bfloat16* kb = qm + ((size_t)bh*NM + j0 + lr)*64 + lg*8;
    bf16x8 b00 = *(const bf16x8*)(kb);
    bf16x8 b01 = *(const bf16x8*)(kb + 32);
    bf16x8 b10 = *(const bf16x8*)(kb + 16*64);
    bf16x8 b11 = *(const bf16x8*)(kb + 16*64 + 32);
    f32x4 s0 = {0.f,0.f,0.f,0.f}, s1 = {0.f,0.f,0.f,0.f};
    s0 = __builtin_amdgcn_mfma_f32_16x16x32_bf16(aq0, b00, s0, 0,0,0);
    s0 = __builtin_amdgcn_mfma_f32_16x16x32_bf16(aq1, b01, s0, 0,0,0);
    s1 = __builtin_amdgcn_mfma_f32_16x16x32_bf16(aq0, b10, s1, 0,0,0);
    s1 = __builtin_amdgcn_mfma_f32_16x16x32_bf16(aq1, b11, s1, 0,0,0);
    #pragma unroll
    for (int r=0;r<4;r++){
      float p0 = __expf(s0[r]*0.125f);
      float p1 = __expf(s1[r]*0.125f);
      pl[w][4*lg+r][lr]    = __float2bfloat16(p0);   // P[i][j] layout
      pl[w][4*lg+r][16+lr] = __float2bfloat16(p1);
      rs[r] += p0 + p1;
    }
    bf16x8 bp = *(const bf16x8*)&pl[w][lr][lg*8];    // B[k=j_local][n=i_local]
    #pragma unroll
    for (int dt=0;dt<4;dt++){
      const __hip_bfloat16* vb = vm + ((size_t)(bh*64 + dt*16 + lr))*NM + j0 + lg*8;
      bf16x8 av = *(const bf16x8*)vb;                // A[m=d][k=j]
      facc[dt] = __builtin_amdgcn_mfma_f32_16x16x32_bf16(av, bp, facc[dt], 0,0,0);
    }
  }
  #pragma unroll
  for (int r=0;r<4;r++){
    float v = rs[r];
    v += __shfl_xor(v,1); v += __shfl_xor(v,2); v += __shfl_xor(v,4); v += __shfl_xor(v,8);
    if (lr==0) rsl[w][4*lg+r] = v;
  }
  __syncthreads();
  float inv = 1.f / rsl[w][lr];
  #pragma unroll
  for (int dt=0;dt<4;dt++){
    #pragma unroll
    for (int r=0;r<4;r++){
      int d = dt*16 + 4*lg + r;                      // FO^T: col=i(lr), row=d
      fo[((size_t)(b*256 + d*4 + h))*NF + i0 + lr] = facc[dt][r]*inv;
    }
  }
}

// ---------------- map-direction attention partials (MFMA, softmax over 13824 feat tokens) ----
// num: [16ic][8bh][64d][512j] f32 partial numerators; cs: [16ic][8bh][512j] partial denominators
__global__ __launch_bounds__(256) void k_mattn(const __hip_bfloat16* __restrict__ qm,
    const __hip_bfloat16* __restrict__ qf, const __hip_bfloat16* __restrict__ vf,
    float* __restrict__ num, float* __restrict__ cs){
  int ic = blockIdx.x, jb = blockIdx.y, bh = blockIdx.z;
  int w = threadIdx.x>>6, l = threadIdx.x&63;
  int lr = l&15, lg = l>>4;
  int jt0 = jb*64 + w*16;
  __shared__ __hip_bfloat16 pl[4][16][40];
  const __hip_bfloat16* ab = qm + ((size_t)bh*NM + jt0 + lr)*64 + lg*8;
  bf16x8 am0 = *(const bf16x8*)(ab);
  bf16x8 am1 = *(const bf16x8*)(ab + 32);
  f32x4 macc[4];
  #pragma unroll
  for (int t=0;t<4;t++){ macc[t][0]=0.f; macc[t][1]=0.f; macc[t][2]=0.f; macc[t][3]=0.f; }
  float csr[4] = {0.f,0.f,0.f,0.f};
  for (int is=0; is<27; is++){
    int i0 = ic*864 + is*32;
    const __hip_bfloat16* fb = qf + ((size_t)bh*NF + i0 + lr)*64 + lg*8;
    bf16x8 f00 = *(const bf16x8*)(fb);
    bf16x8 f01 = *(const bf16x8*)(fb + 32);
    bf16x8 f10 = *(const bf16x8*)(fb + 16*64);
    bf16x8 f11 = *(const bf16x8*)(fb + 16*64 + 32);
    f32x4 s0 = {0.f,0.f,0.f,0.f}, s1 = {0.f,0.f,0.f,0.f};
    s0 = __builtin_amdgcn_mfma_f32_16x16x32_bf16(am0, f00, s0, 0,0,0);   // S^T[j][i]
    s0 = __builtin_amdgcn_mfma_f32_16x16x32_bf16(am1, f01, s0, 0,0,0);
    s1 = __builtin_amdgcn_mfma_f32_16x16x32_bf16(am0, f10, s1, 0,0,0);
    s1 = __builtin_amdgcn_mfma_f32_16x16x32_bf16(am1, f11, s1, 0,0,0);
    #pragma unroll
    for (int r=0;r<4;r++){
      float p0 = __expf(s0[r]*0.125f);
      float p1 = __expf(s1[r]*0.125f);
      pl[w][4*lg+r][lr]    = __float2bfloat16(p0);   // P^T[j][i] layout
      pl[w][4*lg+r][16+lr] = __float2bfloat16(p1);
      csr[r] += p0 + p1;
    }
    bf16x8 bp = *(const bf16x8*)&pl[w][lr][lg*8];    // B[k=i_local][n=j_local]
    #pragma unroll
    for (int dt=0;dt<4;dt++){
      const __hip_bfloat16* vb = vf + ((size_t)(bh*64 + dt*16 + lr))*NF + i0 + lg*8;
      bf16x8 av = *(const bf16x8*)vb;                // A[m=d][k=i]
      macc[dt] = __builtin_amdgcn_mfma_f32_16x16x32_bf16(av, bp, macc[dt], 0,0,0);
    }
  }
  size_t nb = ((size_t)(ic*8 + bh)*64)*512;          // MO^T: col=j(lr), row=d
  #pragma unroll
  for (int dt=0;dt<4;dt++){
    #pragma unroll
    for (int r=0;r<4;r++){
      num[nb + (size_t)(dt*16 + 4*lg + r)*512 + jt0 + lr] = macc[dt][r];
    }
  }
  #pragma unroll
  for (int r=0;r<4;r++){
    float v = csr[r];
    v += __shfl_xor(v,1); v += __shfl_xor(v,2); v += __shfl_xor(v,4); v += __shfl_xor(v,8);
    if (lr==0) cs[(size_t)(ic*8 + bh)*512 + jt0 + 4*lg + r] = v;
  }
}

// ---------------- combine map-dir partials -> ma merged-channel layout ----------------
__global__ void k_comb(const float* __restrict__ num, const float* __restrict__ cs,
                       float* __restrict__ ma){
  int idx = blockIdx.x*256 + threadIdx.x;
  if (idx >= 8*512*64) return;
  int bh = idx>>15; int rem = idx&32767; int j = rem>>6; int d = rem&63;
  float s=0.f, c=0.f;
  for (int ic=0;ic<16;ic++){
    s += num[((size_t)(ic*8+bh)*64 + d)*512 + j];
    c += cs[(size_t)(ic*8+bh)*512 + j];
  }
  int b = bh>>2, h = bh&3;
  ma[((size_t)(b*256 + d*4 + h))*NM + j] = s/c;
}

// ---------------- squeeze-excite MLP (tiny) ----------------
__global__ void k_se(const float2* __restrict__ st, const float* __restrict__ w1, const float* __restrict__ b1,
                     const float* __restrict__ w2, const float* __restrict__ b2, float* __restrict__ sout){
  int b = blockIdx.x; int t = threadIdx.x;
  __shared__ float mean[512]; __shared__ float s1[128];
  mean[t]     = st[b*512 + t].x;
  mean[t+256] = st[b*512 + t + 256].x;
  __syncthreads();
  if (t<128){
    float a = b1[t];
    for (int c=0;c<512;c++) a += w1[t*512+c]*mean[c];
    s1[t] = fmaxf(a, 0.f);
  }
  __syncthreads();
  for (int o=t;o<512;o+=256){
    float a = b2[o];
    for (int c=0;c<128;c++) a += w2[o*128+c]*s1[c];
    sout[b*512+o] = 1.f/(1.f+__expf(-a));
  }
}

extern "C" void kernel_launch(void* const* d_in, const int* in_sizes, int n_in,
                              void* d_out, int out_size, void* d_ws, size_t ws_size,
                              hipStream_t stream){
  const float* x     = (const float*)d_in[0];
  const float* smap  = (const float*)d_in[1];
  const float* wfdw  = (const float*)d_in[2];
  const float* wfpw  = (const float*)d_in[3];
  const float* wmqv  = (const float*)d_in[4];
  const float* wodw  = (const float*)d_in[5];
  const float* wopw  = (const float*)d_in[6];
  const float* wmout = (const float*)d_in[7];
  const float* wexp  = (const float*)d_in[8];
  const float* wdw   = (const float*)d_in[9];
  const float* wse1  = (const float*)d_in[10];
  const float* bse1  = (const float*)d_in[11];
  const float* wse2  = (const float*)d_in[12];
  const float* bse2  = (const float*)d_in[13];
  const float* wpw   = (const float*)d_in[14];

  float* out  = (float*)d_out;                        // [2][128][NF]
  float* mout = out + (size_t)2*128*NF;               // [2][128][NM]

  float* W = (float*)d_ws;
  size_t o = 0;
  __hip_bfloat16* qf = (__hip_bfloat16*)(W + o); o += (size_t)8*NF*32;   // bf16 [8][NF][64]
  __hip_bfloat16* vf = (__hip_bfloat16*)(W + o); o += (size_t)8*NF*32;   // bf16 [8][64][NF]
  float* fdw  = W + o; o += (size_t)2*128*NF;
  float* num  = W + o; o += (size_t)16*8*64*512;
  __hip_bfloat16* qm = (__hip_bfloat16*)(W + o); o += 8*NM*32;           // bf16 [8][512][64]
  __hip_bfloat16* vm = (__hip_bfloat16*)(W + o); o += 8*NM*32;           // bf16 [8][64][512]
  float* csb  = W + o; o += (size_t)16*8*512;
  float* ma   = W + o; o += (size_t)2*256*NM;
  // h2 overlays [0, 2*512*NF) -- all of the above are dead by MBConv's dw stage
  float* h2   = (float*)d_ws;
  float* fo   = W + o; o += (size_t)2*256*NF;
  float* fdw2 = W + o; o += (size_t)2*256*NF;
  float* h1 = fo;                                     // fo+fdw2 contiguous = 2*512*NF
  float* wTf  = W + o; o += 512*128;
  float* wTm  = W + o; o += 512*128;
  float* wTo  = W + o; o += 128*256;
  float* wTmo = W + o; o += 128*256;
  float* wTe  = W + o; o += 512*128;
  float* wTp  = W + o; o += 128*512;
  float2* stA = (float2*)(W+o); o += 512;
  float2* tfA = (float2*)(W+o); o += 512;
  float2* stM = (float2*)(W+o); o += 512;
  float2* tfM = (float2*)(W+o); o += 512;
  float2* stO = (float2*)(W+o); o += 512;
  float2* tfO = (float2*)(W+o); o += 512;
  float2* stH1= (float2*)(W+o); o += 2048;
  float2* tfH1= (float2*)(W+o); o += 2048;
  float2* stH2= (float2*)(W+o); o += 2048;
  float2* tfH = (float2*)(W+o); o += 2048;
  float* sbuf = W + o; o += 1024;
  (void)ws_size; (void)in_sizes; (void)n_in; (void)out_size;

  // weight transposes
  k_transpose<<<256,256,0,stream>>>(wfpw,  wTf, 512,128);
  k_transpose<<<256,256,0,stream>>>(wmqv,  wTm, 512,128);
  k_transpose<<<128,256,0,stream>>>(wopw,  wTo, 128,256);
  k_transpose<<<128,256,0,stream>>>(wmout, wTmo,128,256);
  k_transpose<<<256,256,0,stream>>>(wexp,  wTe, 512,128);
  k_transpose<<<256,256,0,stream>>>(wpw,   wTp, 128,512);

  // feat path: inorm(x) fused into depthwise, then pointwise -> bf16 q/v attn layouts
  k_stats<<<256,256,0,stream>>>(x, stA, NF);
  k_make_tf<<<1,256,0,stream>>>(stA, nullptr, tfA, 256);
  k_dw3t<<<256,256,0,stream>>>(x, wfdw, tfA, fdw, 128, 0);
  k_pw<<<dim3(216,8,2),256,0,stream>>>(fdw, wTf, nullptr,0, 128,512,NF, nullptr, nullptr, qf, vf, 1);

  // map path: inorm(smap) fused into pointwise
  k_stats<<<256,256,0,stream>>>(smap, stM, NM);
  k_make_tf<<<1,256,0,stream>>>(stM, nullptr, tfM, 256);
  k_pw<<<dim3(8,8,2),256,0,stream>>>(smap, wTm, tfM,0, 128,512,NM, nullptr, nullptr, qm, vm, 1);

  // attention, both directions (MFMA)
  k_fattn<<<dim3(216,8),256,0,stream>>>(qf, qm, vm, fo);
  k_mattn<<<dim3(16,8,8),256,0,stream>>>(qm, qf, vf, num, csb);
  k_comb<<<1024,256,0,stream>>>(num, csb, ma);

  // output convs + residuals
  k_dw3t<<<512,256,0,stream>>>(fo, wodw, nullptr, fdw2, 256, 0);
  k_pw<<<dim3(216,2,2),256,0,stream>>>(fdw2, wTo, nullptr,0, 256,128,NF, x, out, nullptr,nullptr, 0);
  k_pw<<<dim3(8,2,2),256,0,stream>>>(ma, wTmo, nullptr,0, 256,128,NM, smap, mout, nullptr,nullptr, 0);

  // MBConv
  k_stats<<<256,256,0,stream>>>(out, stO, NF);
  k_make_tf<<<1,256,0,stream>>>(stO, nullptr, tfO, 256);
  k_pw<<<dim3(216,8,2),256,0,stream>>>(out, wTe, tfO,1, 128,512,NF, nullptr, h1, nullptr,nullptr, 0);

  k_stats<<<1024,256,0,stream>>>(h1, stH1, NF);
  k_make_tf<<<4,256,0,stream>>>(stH1, nullptr, tfH1, 1024);
  k_dw3t<<<1024,256,0,stream>>>(h1, wdw, tfH1, h2, 512, 1);

  k_stats<<<1024,256,0,stream>>>(h2, stH2, NF);
  k_se<<<2,256,0,stream>>>(stH2, wse1,bse1,wse2,bse2, sbuf);
  k_make_tf<<<4,256,0,stream>>>(stH2, sbuf, tfH, 1024);
  k_pw<<<dim3(216,2,2),256,0,stream>>>(h2, wTp, tfH,0, 512,128,NF, out, out, nullptr,nullptr, 0);
}

// Round 2
// 700.694 us; speedup vs baseline: 1.4332x; 1.0540x over previous
//
#include <hip/hip_runtime.h>
#include <hip/hip_bf16.h>
#include <cstddef>

#define NF 13824
#define NM 512

typedef __attribute__((ext_vector_type(8))) short bf16x8;
typedef __attribute__((ext_vector_type(4))) float f32x4;

// ---------------- weight transpose: WT[ci][co] = W[co][ci] ----------------
__global__ void k_transpose(const float* __restrict__ W, float* __restrict__ WT, int Cout, int Cin){
  int idx = blockIdx.x*256 + threadIdx.x;
  if (idx >= Cout*Cin) return;
  int co = idx / Cin, ci = idx % Cin;
  WT[(size_t)ci*Cout + co] = W[idx];
}

// ---------------- per-row (b,c) mean/var over N ----------------
__global__ void k_stats(const float* __restrict__ in, float2* __restrict__ st, int N){
  int row = blockIdx.x;
  const float* p = in + (size_t)row*N;
  float s=0.f, q=0.f;
  for (int i=threadIdx.x; i<N; i+=256){ float v=p[i]; s+=v; q+=v*v; }
  __shared__ float rs[256], rq[256];
  rs[threadIdx.x]=s; rq[threadIdx.x]=q;
  __syncthreads();
  for (int o=128;o>0;o>>=1){
    if (threadIdx.x<o){ rs[threadIdx.x]+=rs[threadIdx.x+o]; rq[threadIdx.x]+=rq[threadIdx.x+o]; }
    __syncthreads();
  }
  if (threadIdx.x==0){
    float m = rs[0]/N;
    float v = rq[0]/N - m*m;
    st[row] = make_float2(m, v>0.f? v:0.f);
  }
}

// ---------------- stats (+ optional SE scale) -> affine (a,b) ----------------
__global__ void k_make_tf(const float2* __restrict__ st, const float* __restrict__ sbuf,
                          float2* __restrict__ tf, int rows){
  int i = blockIdx.x*256 + threadIdx.x;
  if (i>=rows) return;
  float s = sbuf ? sbuf[i] : 1.f;
  float2 mv = st[i];
  float a = s*rsqrtf(s*s*mv.y + 1e-5f);
  tf[i] = make_float2(a, -mv.x*a);
}

// ---------------- depthwise 3x3x3 conv on 24^3 via LDS-staged channel ----------------
__global__ __launch_bounds__(256) void k_dw3t(const float* __restrict__ in, const float* __restrict__ w,
                      const float2* __restrict__ tf, float* __restrict__ out,
                      int C, int relu){
  int bc = blockIdx.x;
  int c = bc % C;
  __shared__ float lds[4 + 26*728];          // 75728 B
  float a = 1.f, bb = 0.f;
  if (tf){ float2 t = tf[bc]; a=t.x; bb=t.y; }

  {
    float4* l4 = (float4*)lds;
    float4 z = make_float4(0.f,0.f,0.f,0.f);
    for (int i=threadIdx.x; i<(4+26*728)/4; i+=256) l4[i] = z;
  }
  __syncthreads();

  const float* pin = in + (size_t)bc*NF;
  for (int i=threadIdx.x; i<NF/4; i+=256){
    int n = i*4;
    int d = n/576, r2 = n%576;
    int h = r2/24, wq = r2%24;
    float4 v = *(const float4*)(pin + n);
    float v0 = a*v.x+bb, v1 = a*v.y+bb, v2 = a*v.z+bb, v3 = a*v.w+bb;
    if (relu){ v0=fmaxf(v0,0.f); v1=fmaxf(v1,0.f); v2=fmaxf(v2,0.f); v3=fmaxf(v3,0.f); }
    *(float4*)(lds + 4 + (d+1)*728 + (h+1)*28 + wq) = make_float4(v0,v1,v2,v3);
  }

  const float* wc = w + c*27;
  float wr[27];
  #pragma unroll
  for (int k=0;k<27;k++) wr[k] = wc[k];
  __syncthreads();

  for (int r = threadIdx.x; r < 576; r += 256){
    int d = r/24, h = r%24;
    float acc[24];
    #pragma unroll
    for (int i=0;i<24;i++) acc[i] = 0.f;
    #pragma unroll
    for (int kd=0;kd<3;kd++){
      #pragma unroll
      for (int kh=0;kh<3;kh++){
        const float* row = lds + 4 + (d+kd)*728 + (h+kh)*28;
        float rr[24];
        #pragma unroll
        for (int q=0;q<6;q++){
          float4 v4 = *(const float4*)(row + 4*q);
          rr[4*q]=v4.x; rr[4*q+1]=v4.y; rr[4*q+2]=v4.z; rr[4*q+3]=v4.w;
        }
        float rl = row[-1];
        float rrgt = row[24];
        float w0 = wr[kd*9+kh*3+0], w1 = wr[kd*9+kh*3+1], w2 = wr[kd*9+kh*3+2];
        acc[0] += w0*rl + w1*rr[0] + w2*rr[1];
        #pragma unroll
        for (int i=1;i<23;i++) acc[i] += w0*rr[i-1] + w1*rr[i] + w2*rr[i+1];
        acc[23] += w0*rr[22] + w1*rr[23] + w2*rrgt;
      }
    }
    float* op = out + (size_t)bc*NF + r*24;
    #pragma unroll
    for (int q=0;q<6;q++)
      *(float4*)(op + 4*q) = make_float4(acc[4*q],acc[4*q+1],acc[4*q+2],acc[4*q+3]);
  }
}

// ---------------- pointwise conv as tiled SGEMM ----------------
__global__ __launch_bounds__(256) void k_pw(const float* __restrict__ in, const float* __restrict__ WT,
                    const float2* __restrict__ tf, int relu,
                    int Cin, int Cout, int N,
                    const float* __restrict__ res,
                    float* __restrict__ out0,
                    __hip_bfloat16* __restrict__ qnm, __hip_bfloat16* __restrict__ vdm,
                    int mode){
  int b = blockIdx.z;
  int n0 = blockIdx.x*64, co0 = blockIdx.y*64;
  int tx = threadIdx.x & 15, ty = threadIdx.x >> 4;
  __shared__ float wl[32][68];
  __shared__ float il[32][68];
  float acc[4][4] = {};
  const float* inb = in + (size_t)b*Cin*N;
  for (int c0=0;c0<Cin;c0+=32){
    __syncthreads();
    {
      int cc = threadIdx.x & 63, g = threadIdx.x >> 6;
      #pragma unroll
      for (int rr=0;rr<8;rr++){
        int ci = g + 4*rr;
        wl[ci][cc] = WT[(size_t)(c0+ci)*Cout + co0 + cc];
        float v = inb[(size_t)(c0+ci)*N + n0 + cc];
        if (tf){ float2 t = tf[b*Cin + c0 + ci]; v = t.x*v + t.y; }
        if (relu) v = fmaxf(v, 0.f);
        il[ci][cc] = v;
      }
    }
    __syncthreads();
    #pragma unroll
    for (int ci=0;ci<32;ci++){
      float4 a4 = *(const float4*)&wl[ci][ty*4];
      float4 b4 = *(const float4*)&il[ci][tx*4];
      acc[0][0]+=a4.x*b4.x; acc[0][1]+=a4.x*b4.y; acc[0][2]+=a4.x*b4.z; acc[0][3]+=a4.x*b4.w;
      acc[1][0]+=a4.y*b4.x; acc[1][1]+=a4.y*b4.y; acc[1][2]+=a4.y*b4.z; acc[1][3]+=a4.y*b4.w;
      acc[2][0]+=a4.z*b4.x; acc[2][1]+=a4.z*b4.y; acc[2][2]+=a4.z*b4.z; acc[2][3]+=a4.z*b4.w;
      acc[3][0]+=a4.w*b4.x; acc[3][1]+=a4.w*b4.y; acc[3][2]+=a4.w*b4.z; acc[3][3]+=a4.w*b4.w;
    }
  }
  if (mode==0){
    #pragma unroll
    for (int i=0;i<4;i++){
      int co = co0 + ty*4 + i;
      float* op = out0 + ((size_t)b*Cout + co)*N;
      #pragma unroll
      for (int j=0;j<4;j++){
        int n = n0 + tx*4 + j;
        float v = acc[i][j];
        if (res) v += res[((size_t)b*Cout + co)*N + n];
        op[n] = v;
      }
    }
  } else {
    int ccbase = (co0 & 255) + ty*4;
    int dd = ccbase >> 2;
    bool isq = (co0 < 256);
    #pragma unroll
    for (int i=0;i<4;i++){
      int bhid = b*4 + i;
      #pragma unroll
      for (int j=0;j<4;j++){
        int n = n0 + tx*4 + j;
        __hip_bfloat16 v = __float2bfloat16(acc[i][j]);
        if (isq) qnm[((size_t)bhid*N + n)*64 + dd] = v;
        else     vdm[((size_t)(bhid*64 + dd))*N + n] = v;
      }
    }
  }
}

// ---------------- feat-direction attention (MFMA, no-max softmax over 512 map tokens) ----
// 32 i-rows per wave (2 fragment groups), A/B register double-buffer of K/V tiles.
__global__ __launch_bounds__(256) void k_fattn(const __hip_bfloat16* __restrict__ qf,
    const __hip_bfloat16* __restrict__ qm, const __hip_bfloat16* __restrict__ vm,
    float* __restrict__ fo){
  int bh = blockIdx.y, b = bh>>2, h = bh&3;
  int w = threadIdx.x>>6, l = threadIdx.x&63;
  int i0 = blockIdx.x*128 + w*32;
  int lr = l&15, lg = l>>4;
  __shared__ __hip_bfloat16 pl[4][2][2][16][40];
  __shared__ float rsl[4][32];
  bf16x8 aq[2][2];
  #pragma unroll
  for (int g=0; g<2; g++){
    const __hip_bfloat16* qb = qf + ((size_t)bh*NF + i0 + g*16 + lr)*64 + lg*8;
    aq[g][0] = *(const bf16x8*)(qb);
    aq[g][1] = *(const bf16x8*)(qb + 32);
  }
  f32x4 facc[2][4];
  #pragma unroll
  for (int g=0; g<2; g++)
    #pragma unroll
    for (int t=0;t<4;t++){ facc[g][t][0]=0.f; facc[g][t][1]=0.f; facc[g][t][2]=0.f; facc[g][t][3]=0.f; }
  float rs[2][4] = {};
  const __hip_bfloat16* kbase = qm + ((size_t)bh*NM + lr)*64 + lg*8;
  const __hip_bfloat16* vbase = vm + ((size_t)bh*64 + lr)*NM + lg*8;

  auto fcomp = [&](bf16x8 K0, bf16x8 K1, bf16x8 K2, bf16x8 K3,
                   bf16x8 V0, bf16x8 V1, bf16x8 V2, bf16x8 V3, int SET){
    #pragma unroll
    for (int g=0; g<2; g++){
      f32x4 s0 = {0.f,0.f,0.f,0.f}, s1 = {0.f,0.f,0.f,0.f};
      s0 = __builtin_amdgcn_mfma_f32_16x16x32_bf16(aq[g][0], K0, s0, 0,0,0);
      s0 = __builtin_amdgcn_mfma_f32_16x16x32_bf16(aq[g][1], K1, s0, 0,0,0);
      s1 = __builtin_amdgcn_mfma_f32_16x16x32_bf16(aq[g][0], K2, s1, 0,0,0);
      s1 = __builtin_amdgcn_mfma_f32_16x16x32_bf16(aq[g][1], K3, s1, 0,0,0);
      #pragma unroll
      for (int r=0;r<4;r++){
        float p0 = __expf(s0[r]*0.125f);
        float p1 = __expf(s1[r]*0.125f);
        pl[w][SET][g][4*lg+r][lr]    = __float2bfloat16(p0);
        pl[w][SET][g][4*lg+r][16+lr] = __float2bfloat16(p1);
        rs[g][r] += p0 + p1;
      }
    }
    #pragma unroll
    for (int g=0; g<2; g++){
      bf16x8 bp = *(const bf16x8*)&pl[w][SET][g][lr][lg*8];
      facc[g][0] = __builtin_amdgcn_mfma_f32_16x16x32_bf16(V0, bp, facc[g][0], 0,0,0);
      facc[g][1] = __builtin_amdgcn_mfma_f32_16x16x32_bf16(V1, bp, facc[g][1], 0,0,0);
      facc[g][2] = __builtin_amdgcn_mfma_f32_16x16x32_bf16(V2, bp, facc[g][2], 0,0,0);
      facc[g][3] = __builtin_amdgcn_mfma_f32_16x16x32_bf16(V3, bp, facc[g][3], 0,0,0);
    }
  };

  bf16x8 kA0,kA1,kA2,kA3,vA0,vA1,vA2,vA3;
  bf16x8 kB0,kB1,kB2,kB3,vB0,vB1,vB2,vB3;
  #define FLOAD(KP,VP,J0) \
    KP##0 = *(const bf16x8*)(kbase + (size_t)(J0)*64); \
    KP##1 = *(const bf16x8*)(kbase + (size_t)(J0)*64 + 32); \
    KP##2 = *(const bf16x8*)(kbase + (size_t)(J0)*64 + 1024); \
    KP##3 = *(const bf16x8*)(kbase + (size_t)(J0)*64 + 1056); \
    VP##0 = *(const bf16x8*)(vbase + (J0)); \
    VP##1 = *(const bf16x8*)(vbase + 16*NM + (J0)); \
    VP##2 = *(const bf16x8*)(vbase + 32*NM + (J0)); \
    VP##3 = *(const bf16x8*)(vbase + 48*NM + (J0));

  FLOAD(kA,vA,0)
  for (int jt=0; jt<16; jt+=2){
    FLOAD(kB,vB,(jt+1)*32)
    fcomp(kA0,kA1,kA2,kA3,vA0,vA1,vA2,vA3,0);
    if (jt+2 < 16){ FLOAD(kA,vA,(jt+2)*32) }
    fcomp(kB0,kB1,kB2,kB3,vB0,vB1,vB2,vB3,1);
  }
  #undef FLOAD

  #pragma unroll
  for (int g=0; g<2; g++)
    #pragma unroll
    for (int r=0;r<4;r++){
      float v = rs[g][r];
      v += __shfl_xor(v,1); v += __shfl_xor(v,2); v += __shfl_xor(v,4); v += __shfl_xor(v,8);
      if (lr==0) rsl[w][g*16 + 4*lg+r] = v;
    }
  __syncthreads();
  #pragma unroll
  for (int g=0; g<2; g++){
    float inv = 1.f / rsl[w][g*16 + lr];
    #pragma unroll
    for (int dt=0; dt<4; dt++){
      #pragma unroll
      for (int r=0;r<4;r++){
        int d = dt*16 + 4*lg + r;
        fo[((size_t)(b*256 + d*4 + h))*NF + i0 + g*16 + lr] = facc[g][dt][r]*inv;
      }
    }
  }
}

// ---------------- map-direction attention partials (A/B double-buffered i-tiles) ----
__global__ __launch_bounds__(256) void k_mattn(const __hip_bfloat16* __restrict__ qm,
    const __hip_bfloat16* __restrict__ qf, const __hip_bfloat16* __restrict__ vf,
    float* __restrict__ num, float* __restrict__ cs){
  int ic = blockIdx.x, jb = blockIdx.y, bh = blockIdx.z;
  int w = threadIdx.x>>6, l = threadIdx.x&63;
  int lr = l&15, lg = l>>4;
  int jt0 = jb*64 + w*16;
  __shared__ __hip_bfloat16 pl[4][2][16][40];
  const __hip_bfloat16* ab = qm + ((size_t)bh*NM + jt0 + lr)*64 + lg*8;
  bf16x8 am0 = *(const bf16x8*)(ab);
  bf16x8 am1 = *(const bf16x8*)(ab + 32);
  f32x4 macc[4];
  #pragma unroll
  for (int t=0;t<4;t++){ macc[t][0]=0.f; macc[t][1]=0.f; macc[t][2]=0.f; macc[t][3]=0.f; }
  float csr[4] = {0.f,0.f,0.f,0.f};
  const __hip_bfloat16* fbase  = qf + ((size_t)bh*NF + lr)*64 + lg*8;
  const __hip_bfloat16* vfbase = vf + ((size_t)bh*64 + lr)*NF + lg*8;

  auto mcomp = [&](bf16x8 F0, bf16x8 F1, bf16x8 F2, bf16x8 F3,
                   bf16x8 V0, bf16x8 V1, bf16x8 V2, bf16x8 V3, int SET){
    f32x4 s0 = {0.f,0.f,0.f,0.f}, s1 = {0.f,0.f,0.f,0.f};
    s0 = __builtin_amdgcn_mfma_f32_16x16x32_bf16(am0, F0, s0, 0,0,0);
    s0 = __builtin_amdgcn_mfma_f32_16x16x32_bf16(am1, F1, s0, 0,0,0);
    s1 = __builtin_amdgcn_mfma_f32_16x16x32_bf16(am0, F2, s1, 0,0,0);
    s1 = __builtin_amdgcn_mfma_f32_16x16x32_bf16(am1, F3, s1, 0,0,0);
    #pragma unroll
    for (int r=0;r<4;r++){
      float p0 = __expf(s0[r]*0.125f);
      float p1 = __expf(s1[r]*0.125f);
      pl[w][SET][4*lg+r][lr]    = __float2bfloat16(p0);
      pl[w][SET][4*lg+r][16+lr] = __float2bfloat16(p1);
      csr[r] += p0 + p1;
    }
    bf16x8 bp = *(const bf16x8*)&pl[w][SET][lr][lg*8];
    macc[0] = __builtin_amdgcn_mfma_f32_16x16x32_bf16(V0, bp, macc[0], 0,0,0);
    macc[1] = __builtin_amdgcn_mfma_f32_16x16x32_bf16(V1, bp, macc[1], 0,0,0);
    macc[2] = __builtin_amdgcn_mfma_f32_16x16x32_bf16(V2, bp, macc[2], 0,0,0);
    macc[3] = __builtin_amdgcn_mfma_f32_16x16x32_bf16(V3, bp, macc[3], 0,0,0);
  };

  bf16x8 fA0,fA1,fA2,fA3,vA0,vA1,vA2,vA3;
  bf16x8 fB0,fB1,fB2,fB3,vB0,vB1,vB2,vB3;
  #define MLOAD(FP,VP,I0) \
    FP##0 = *(const bf16x8*)(fbase + (size_t)(I0)*64); \
    FP##1 = *(const bf16x8*)(fbase + (size_t)(I0)*64 + 32); \
    FP##2 = *(const bf16x8*)(fbase + (size_t)(I0)*64 + 1024); \
    FP##3 = *(const bf16x8*)(fbase + (size_t)(I0)*64 + 1056); \
    VP##0 = *(const bf16x8*)(vfbase + (size_t)(I0)); \
    VP##1 = *(const bf16x8*)(vfbase + (size_t)16*NF + (I0)); \
    VP##2 = *(const bf16x8*)(vfbase + (size_t)32*NF + (I0)); \
    VP##3 = *(const bf16x8*)(vfbase + (size_t)48*NF + (I0));

  int ibase = ic*864;
  MLOAD(fA,vA, ibase)
  for (int is=0; is<26; is+=2){
    MLOAD(fB,vB, ibase + (is+1)*32)
    mcomp(fA0,fA1,fA2,fA3,vA0,vA1,vA2,vA3,0);
    MLOAD(fA,vA, ibase + (is+2)*32)
    mcomp(fB0,fB1,fB2,fB3,vB0,vB1,vB2,vB3,1);
  }
  mcomp(fA0,fA1,fA2,fA3,vA0,vA1,vA2,vA3,0);
  #undef MLOAD

  size_t nb = ((size_t)(ic*8 + bh)*64)*512;
  #pragma unroll
  for (int dt=0;dt<4;dt++){
    #pragma unroll
    for (int r=0;r<4;r++){
      num[nb + (size_t)(dt*16 + 4*lg + r)*512 + jt0 + lr] = macc[dt][r];
    }
  }
  #pragma unroll
  for (int r=0;r<4;r++){
    float v = csr[r];
    v += __shfl_xor(v,1); v += __shfl_xor(v,2); v += __shfl_xor(v,4); v += __shfl_xor(v,8);
    if (lr==0) cs[(size_t)(ic*8 + bh)*512 + jt0 + 4*lg + r] = v;
  }
}

// ---------------- combine map-dir partials -> ma merged-channel layout ----------------
__global__ void k_comb(const float* __restrict__ num, const float* __restrict__ cs,
                       float* __restrict__ ma){
  int idx = blockIdx.x*256 + threadIdx.x;
  if (idx >= 8*512*64) return;
  int bh = idx>>15; int rem = idx&32767; int j = rem>>6; int d = rem&63;
  float s=0.f, c=0.f;
  for (int ic=0;ic<16;ic++){
    s += num[((size_t)(ic*8+bh)*64 + d)*512 + j];
    c += cs[(size_t)(ic*8+bh)*512 + j];
  }
  int b = bh>>2, h = bh&3;
  ma[((size_t)(b*256 + d*4 + h))*NM + j] = s/c;
}

// ---------------- squeeze-excite MLP (tiny) ----------------
__global__ void k_se(const float2* __restrict__ st, const float* __restrict__ w1, const float* __restrict__ b1,
                     const float* __restrict__ w2, const float* __restrict__ b2, float* __restrict__ sout){
  int b = blockIdx.x; int t = threadIdx.x;
  __shared__ float mean[512]; __shared__ float s1[128];
  mean[t]     = st[b*512 + t].x;
  mean[t+256] = st[b*512 + t + 256].x;
  __syncthreads();
  if (t<128){
    float a = b1[t];
    for (int c=0;c<512;c++) a += w1[t*512+c]*mean[c];
    s1[t] = fmaxf(a, 0.f);
  }
  __syncthreads();
  for (int o=t;o<512;o+=256){
    float a = b2[o];
    for (int c=0;c<128;c++) a += w2[o*128+c]*s1[c];
    sout[b*512+o] = 1.f/(1.f+__expf(-a));
  }
}

extern "C" void kernel_launch(void* const* d_in, const int* in_sizes, int n_in,
                              void* d_out, int out_size, void* d_ws, size_t ws_size,
                              hipStream_t stream){
  const float* x     = (const float*)d_in[0];
  const float* smap  = (const float*)d_in[1];
  const float* wfdw  = (const float*)d_in[2];
  const float* wfpw  = (const float*)d_in[3];
  const float* wmqv  = (const float*)d_in[4];
  const float* wodw  = (const float*)d_in[5];
  const float* wopw  = (const float*)d_in[6];
  const float* wmout = (const float*)d_in[7];
  const float* wexp  = (const float*)d_in[8];
  const float* wdw   = (const float*)d_in[9];
  const float* wse1  = (const float*)d_in[10];
  const float* bse1  = (const float*)d_in[11];
  const float* wse2  = (const float*)d_in[12];
  const float* bse2  = (const float*)d_in[13];
  const float* wpw   = (const float*)d_in[14];

  float* out  = (float*)d_out;                        // [2][128][NF]
  float* mout = out + (size_t)2*128*NF;               // [2][128][NM]

  float* W = (float*)d_ws;
  size_t o = 0;
  __hip_bfloat16* qf = (__hip_bfloat16*)(W + o); o += (size_t)8*NF*32;   // bf16 [8][NF][64]
  __hip_bfloat16* vf = (__hip_bfloat16*)(W + o); o += (size_t)8*NF*32;   // bf16 [8][64][NF]
  float* fdw  = W + o; o += (size_t)2*128*NF;
  float* num  = W + o; o += (size_t)16*8*64*512;
  __hip_bfloat16* qm = (__hip_bfloat16*)(W + o); o += 8*NM*32;           // bf16 [8][512][64]
  __hip_bfloat16* vm = (__hip_bfloat16*)(W + o); o += 8*NM*32;           // bf16 [8][64][512]
  float* csb  = W + o; o += (size_t)16*8*512;
  float* ma   = W + o; o += (size_t)2*256*NM;
  float* h2   = (float*)d_ws;
  float* fo   = W + o; o += (size_t)2*256*NF;
  float* fdw2 = W + o; o += (size_t)2*256*NF;
  float* h1 = fo;
  float* wTf  = W + o; o += 512*128;
  float* wTm  = W + o; o += 512*128;
  float* wTo  = W + o; o += 128*256;
  float* wTmo = W + o; o += 128*256;
  float* wTe  = W + o; o += 512*128;
  float* wTp  = W + o; o += 128*512;
  float2* stA = (float2*)(W+o); o += 512;
  float2* tfA = (float2*)(W+o); o += 512;
  float2* stM = (float2*)(W+o); o += 512;
  float2* tfM = (float2*)(W+o); o += 512;
  float2* stO = (float2*)(W+o); o += 512;
  float2* tfO = (float2*)(W+o); o += 512;
  float2* stH1= (float2*)(W+o); o += 2048;
  float2* tfH1= (float2*)(W+o); o += 2048;
  float2* stH2= (float2*)(W+o); o += 2048;
  float2* tfH = (float2*)(W+o); o += 2048;
  float* sbuf = W + o; o += 1024;
  (void)ws_size; (void)in_sizes; (void)n_in; (void)out_size;

  // weight transposes
  k_transpose<<<256,256,0,stream>>>(wfpw,  wTf, 512,128);
  k_transpose<<<256,256,0,stream>>>(wmqv,  wTm, 512,128);
  k_transpose<<<128,256,0,stream>>>(wopw,  wTo, 128,256);
  k_transpose<<<128,256,0,stream>>>(wmout, wTmo,128,256);
  k_transpose<<<256,256,0,stream>>>(wexp,  wTe, 512,128);
  k_transpose<<<256,256,0,stream>>>(wpw,   wTp, 128,512);

  // feat path
  k_stats<<<256,256,0,stream>>>(x, stA, NF);
  k_make_tf<<<1,256,0,stream>>>(stA, nullptr, tfA, 256);
  k_dw3t<<<256,256,0,stream>>>(x, wfdw, tfA, fdw, 128, 0);
  k_pw<<<dim3(216,8,2),256,0,stream>>>(fdw, wTf, nullptr,0, 128,512,NF, nullptr, nullptr, qf, vf, 1);

  // map path
  k_stats<<<256,256,0,stream>>>(smap, stM, NM);
  k_make_tf<<<1,256,0,stream>>>(stM, nullptr, tfM, 256);
  k_pw<<<dim3(8,8,2),256,0,stream>>>(smap, wTm, tfM,0, 128,512,NM, nullptr, nullptr, qm, vm, 1);

  // attention, both directions (MFMA)
  k_fattn<<<dim3(108,8),256,0,stream>>>(qf, qm, vm, fo);
  k_mattn<<<dim3(16,8,8),256,0,stream>>>(qm, qf, vf, num, csb);
  k_comb<<<1024,256,0,stream>>>(num, csb, ma);

  // output convs + residuals
  k_dw3t<<<512,256,0,stream>>>(fo, wodw, nullptr, fdw2, 256, 0);
  k_pw<<<dim3(216,2,2),256,0,stream>>>(fdw2, wTo, nullptr,0, 256,128,NF, x, out, nullptr,nullptr, 0);
  k_pw<<<dim3(8,2,2),256,0,stream>>>(ma, wTmo, nullptr,0, 256,128,NM, smap, mout, nullptr,nullptr, 0);

  // MBConv
  k_stats<<<256,256,0,stream>>>(out, stO, NF);
  k_make_tf<<<1,256,0,stream>>>(stO, nullptr, tfO, 256);
  k_pw<<<dim3(216,8,2),256,0,stream>>>(out, wTe, tfO,1, 128,512,NF, nullptr, h1, nullptr,nullptr, 0);

  k_stats<<<1024,256,0,stream>>>(h1, stH1, NF);
  k_make_tf<<<4,256,0,stream>>>(stH1, nullptr, tfH1, 1024);
  k_dw3t<<<1024,256,0,stream>>>(h1, wdw, tfH1, h2, 512, 1);

  k_stats<<<1024,256,0,stream>>>(h2, stH2, NF);
  k_se<<<2,256,0,stream>>>(stH2, wse1,bse1,wse2,bse2, sbuf);
  k_make_tf<<<4,256,0,stream>>>(stH2, sbuf, tfH, 1024);
  k_pw<<<dim3(216,2,2),256,0,stream>>>(h2, wTp, tfH,0, 512,128,NF, out, out, nullptr,nullptr, 0);
}

// Round 3
// 666.149 us; speedup vs baseline: 1.5075x; 1.0519x over previous
//
#include <hip/hip_runtime.h>
#include <hip/hip_bf16.h>
#include <cstddef>

#define NF 13824
#define NM 512
#define NIC 27

typedef __attribute__((ext_vector_type(8))) short bf16x8;
typedef __attribute__((ext_vector_type(4))) float f32x4;

// ---------------- merged weight transposes: WT[ci][co] = W[co][ci] ----------------
__global__ void k_transpose6(const float* __restrict__ s0, float* __restrict__ d0,
                             const float* __restrict__ s1, float* __restrict__ d1,
                             const float* __restrict__ s2, float* __restrict__ d2,
                             const float* __restrict__ s3, float* __restrict__ d3,
                             const float* __restrict__ s4, float* __restrict__ d4,
                             const float* __restrict__ s5, float* __restrict__ d5){
  const float* W; float* WT; int Cout, Cin;
  switch (blockIdx.y){
    case 0: W=s0; WT=d0; Cout=512; Cin=128; break;
    case 1: W=s1; WT=d1; Cout=512; Cin=128; break;
    case 2: W=s2; WT=d2; Cout=128; Cin=256; break;
    case 3: W=s3; WT=d3; Cout=128; Cin=256; break;
    case 4: W=s4; WT=d4; Cout=512; Cin=128; break;
    default: W=s5; WT=d5; Cout=128; Cin=512; break;
  }
  int idx = blockIdx.x*256 + threadIdx.x;
  if (idx >= Cout*Cin) return;
  int co = idx / Cin, ci = idx % Cin;
  WT[(size_t)ci*Cout + co] = W[idx];
}

// ---------------- per-row (b,c) mean/var over N (+ fused affine when tf!=null) ----------------
__global__ void k_stats(const float* __restrict__ in, float2* __restrict__ st, int N,
                        float2* __restrict__ tf){
  int row = blockIdx.x;
  const float* p = in + (size_t)row*N;
  float s=0.f, q=0.f;
  int n4 = N/4;
  for (int i=threadIdx.x; i<n4; i+=256){
    float4 v = *(const float4*)(p + i*4);
    s += v.x+v.y+v.z+v.w;
    q += v.x*v.x+v.y*v.y+v.z*v.z+v.w*v.w;
  }
  __shared__ float rs[256], rq[256];
  rs[threadIdx.x]=s; rq[threadIdx.x]=q;
  __syncthreads();
  for (int o=128;o>0;o>>=1){
    if (threadIdx.x<o){ rs[threadIdx.x]+=rs[threadIdx.x+o]; rq[threadIdx.x]+=rq[threadIdx.x+o]; }
    __syncthreads();
  }
  if (threadIdx.x==0){
    float m = rs[0]/N;
    float v = rq[0]/N - m*m;
    if (v<0.f) v=0.f;
    st[row] = make_float2(m, v);
    if (tf){
      float a = rsqrtf(v + 1e-5f);
      tf[row] = make_float2(a, -m*a);
    }
  }
}

// ---------------- stats (+ SE scale) -> affine (a,b) ----------------
__global__ void k_make_tf(const float2* __restrict__ st, const float* __restrict__ sbuf,
                          float2* __restrict__ tf, int rows){
  int i = blockIdx.x*256 + threadIdx.x;
  if (i>=rows) return;
  float s = sbuf ? sbuf[i] : 1.f;
  float2 mv = st[i];
  float a = s*rsqrtf(s*s*mv.y + 1e-5f);
  tf[i] = make_float2(a, -mv.x*a);
}

// ---------------- depthwise 3x3x3 conv on 24^3 via LDS-staged channel ----------------
__global__ __launch_bounds__(256) void k_dw3t(const float* __restrict__ in, const float* __restrict__ w,
                      const float2* __restrict__ tf, float* __restrict__ out,
                      int C, int relu){
  int bc = blockIdx.x;
  int c = bc % C;
  __shared__ float lds[4 + 26*728];          // 75728 B
  float a = 1.f, bb = 0.f;
  if (tf){ float2 t = tf[bc]; a=t.x; bb=t.y; }

  {
    float4* l4 = (float4*)lds;
    float4 z = make_float4(0.f,0.f,0.f,0.f);
    for (int i=threadIdx.x; i<(4+26*728)/4; i+=256) l4[i] = z;
  }
  __syncthreads();

  const float* pin = in + (size_t)bc*NF;
  for (int i=threadIdx.x; i<NF/4; i+=256){
    int n = i*4;
    int d = n/576, r2 = n%576;
    int h = r2/24, wq = r2%24;
    float4 v = *(const float4*)(pin + n);
    float v0 = a*v.x+bb, v1 = a*v.y+bb, v2 = a*v.z+bb, v3 = a*v.w+bb;
    if (relu){ v0=fmaxf(v0,0.f); v1=fmaxf(v1,0.f); v2=fmaxf(v2,0.f); v3=fmaxf(v3,0.f); }
    *(float4*)(lds + 4 + (d+1)*728 + (h+1)*28 + wq) = make_float4(v0,v1,v2,v3);
  }

  const float* wc = w + c*27;
  float wr[27];
  #pragma unroll
  for (int k=0;k<27;k++) wr[k] = wc[k];
  __syncthreads();

  for (int r = threadIdx.x; r < 576; r += 256){
    int d = r/24, h = r%24;
    float acc[24];
    #pragma unroll
    for (int i=0;i<24;i++) acc[i] = 0.f;
    #pragma unroll
    for (int kd=0;kd<3;kd++){
      #pragma unroll
      for (int kh=0;kh<3;kh++){
        const float* row = lds + 4 + (d+kd)*728 + (h+kh)*28;
        float rr[24];
        #pragma unroll
        for (int q=0;q<6;q++){
          float4 v4 = *(const float4*)(row + 4*q);
          rr[4*q]=v4.x; rr[4*q+1]=v4.y; rr[4*q+2]=v4.z; rr[4*q+3]=v4.w;
        }
        float rl = row[-1];
        float rrgt = row[24];
        float w0 = wr[kd*9+kh*3+0], w1 = wr[kd*9+kh*3+1], w2 = wr[kd*9+kh*3+2];
        acc[0] += w0*rl + w1*rr[0] + w2*rr[1];
        #pragma unroll
        for (int i=1;i<23;i++) acc[i] += w0*rr[i-1] + w1*rr[i] + w2*rr[i+1];
        acc[23] += w0*rr[22] + w1*rr[23] + w2*rrgt;
      }
    }
    float* op = out + (size_t)bc*NF + r*24;
    #pragma unroll
    for (int q=0;q<6;q++)
      *(float4*)(op + 4*q) = make_float4(acc[4*q],acc[4*q+1],acc[4*q+2],acc[4*q+3]);
  }
}

// ---------------- pointwise conv as tiled SGEMM (register-prefetch pipelined) ----------------
__global__ __launch_bounds__(256) void k_pw(const float* __restrict__ in, const float* __restrict__ WT,
                    const float2* __restrict__ tf, int relu,
                    int Cin, int Cout, int N,
                    const float* __restrict__ res,
                    float* __restrict__ out0,
                    __hip_bfloat16* __restrict__ qnm, __hip_bfloat16* __restrict__ vdm,
                    int mode){
  int b = blockIdx.z;
  int n0 = blockIdx.x*64, co0 = blockIdx.y*64;
  int tx = threadIdx.x & 15, ty = threadIdx.x >> 4;
  int cc = threadIdx.x & 63, g = threadIdx.x >> 6;
  __shared__ float wl[32][68];
  __shared__ float il[32][68];
  float acc[4][4] = {};
  const float* inb = in + (size_t)b*Cin*N;

  float rw[8], rv[8], ta[8], tb[8];
  #pragma unroll
  for (int rr=0;rr<8;rr++){ ta[rr]=1.f; tb[rr]=0.f; }
  #pragma unroll
  for (int rr=0;rr<8;rr++){
    int ci = g + 4*rr;
    rw[rr] = WT[(size_t)ci*Cout + co0 + cc];
    rv[rr] = inb[(size_t)ci*N + n0 + cc];
    if (tf){ float2 t = tf[b*Cin + ci]; ta[rr]=t.x; tb[rr]=t.y; }
  }

  for (int c0=0;c0<Cin;c0+=32){
    __syncthreads();
    #pragma unroll
    for (int rr=0;rr<8;rr++){
      int ci = g + 4*rr;
      wl[ci][cc] = rw[rr];
      float v = ta[rr]*rv[rr] + tb[rr];
      if (relu) v = fmaxf(v, 0.f);
      il[ci][cc] = v;
    }
    __syncthreads();
    if (c0+32 < Cin){
      int c0n = c0+32;
      #pragma unroll
      for (int rr=0;rr<8;rr++){
        int ci = g + 4*rr;
        rw[rr] = WT[(size_t)(c0n+ci)*Cout + co0 + cc];
        rv[rr] = inb[(size_t)(c0n+ci)*N + n0 + cc];
        if (tf){ float2 t = tf[b*Cin + c0n + ci]; ta[rr]=t.x; tb[rr]=t.y; }
      }
    }
    #pragma unroll
    for (int ci=0;ci<32;ci++){
      float4 a4 = *(const float4*)&wl[ci][ty*4];
      float4 b4 = *(const float4*)&il[ci][tx*4];
      acc[0][0]+=a4.x*b4.x; acc[0][1]+=a4.x*b4.y; acc[0][2]+=a4.x*b4.z; acc[0][3]+=a4.x*b4.w;
      acc[1][0]+=a4.y*b4.x; acc[1][1]+=a4.y*b4.y; acc[1][2]+=a4.y*b4.z; acc[1][3]+=a4.y*b4.w;
      acc[2][0]+=a4.z*b4.x; acc[2][1]+=a4.z*b4.y; acc[2][2]+=a4.z*b4.z; acc[2][3]+=a4.z*b4.w;
      acc[3][0]+=a4.w*b4.x; acc[3][1]+=a4.w*b4.y; acc[3][2]+=a4.w*b4.z; acc[3][3]+=a4.w*b4.w;
    }
  }
  if (mode==0){
    #pragma unroll
    for (int i=0;i<4;i++){
      int co = co0 + ty*4 + i;
      float* op = out0 + ((size_t)b*Cout + co)*N;
      #pragma unroll
      for (int j=0;j<4;j++){
        int n = n0 + tx*4 + j;
        float v = acc[i][j];
        if (res) v += res[((size_t)b*Cout + co)*N + n];
        op[n] = v;
      }
    }
  } else {
    int ccbase = (co0 & 255) + ty*4;
    int dd = ccbase >> 2;
    bool isq = (co0 < 256);
    #pragma unroll
    for (int i=0;i<4;i++){
      int bhid = b*4 + i;
      #pragma unroll
      for (int j=0;j<4;j++){
        int n = n0 + tx*4 + j;
        __hip_bfloat16 v = __float2bfloat16(acc[i][j]);
        if (isq) qnm[((size_t)bhid*N + n)*64 + dd] = v;
        else     vdm[((size_t)(bhid*64 + dd))*N + n] = v;
      }
    }
  }
}

// ---------------- feat-direction attention (MFMA, no-max softmax over 512 map tokens) ----
__global__ __launch_bounds__(256) void k_fattn(const __hip_bfloat16* __restrict__ qf,
    const __hip_bfloat16* __restrict__ qm, const __hip_bfloat16* __restrict__ vm,
    float* __restrict__ fo){
  int bh = blockIdx.y, b = bh>>2, h = bh&3;
  int w = threadIdx.x>>6, l = threadIdx.x&63;
  int i0 = blockIdx.x*128 + w*32;
  int lr = l&15, lg = l>>4;
  __shared__ __hip_bfloat16 pl[4][2][2][16][40];
  __shared__ float rsl[4][32];
  bf16x8 aq[2][2];
  #pragma unroll
  for (int g=0; g<2; g++){
    const __hip_bfloat16* qb = qf + ((size_t)bh*NF + i0 + g*16 + lr)*64 + lg*8;
    aq[g][0] = *(const bf16x8*)(qb);
    aq[g][1] = *(const bf16x8*)(qb + 32);
  }
  f32x4 facc[2][4];
  #pragma unroll
  for (int g=0; g<2; g++)
    #pragma unroll
    for (int t=0;t<4;t++){ facc[g][t][0]=0.f; facc[g][t][1]=0.f; facc[g][t][2]=0.f; facc[g][t][3]=0.f; }
  float rs[2][4] = {};
  const __hip_bfloat16* kbase = qm + ((size_t)bh*NM + lr)*64 + lg*8;
  const __hip_bfloat16* vbase = vm + ((size_t)bh*64 + lr)*NM + lg*8;

  auto fcomp = [&](bf16x8 K0, bf16x8 K1, bf16x8 K2, bf16x8 K3,
                   bf16x8 V0, bf16x8 V1, bf16x8 V2, bf16x8 V3, int SET){
    #pragma unroll
    for (int g=0; g<2; g++){
      f32x4 s0 = {0.f,0.f,0.f,0.f}, s1 = {0.f,0.f,0.f,0.f};
      s0 = __builtin_amdgcn_mfma_f32_16x16x32_bf16(aq[g][0], K0, s0, 0,0,0);
      s0 = __builtin_amdgcn_mfma_f32_16x16x32_bf16(aq[g][1], K1, s0, 0,0,0);
      s1 = __builtin_amdgcn_mfma_f32_16x16x32_bf16(aq[g][0], K2, s1, 0,0,0);
      s1 = __builtin_amdgcn_mfma_f32_16x16x32_bf16(aq[g][1], K3, s1, 0,0,0);
      #pragma unroll
      for (int r=0;r<4;r++){
        float p0 = __expf(s0[r]*0.125f);
        float p1 = __expf(s1[r]*0.125f);
        pl[w][SET][g][4*lg+r][lr]    = __float2bfloat16(p0);
        pl[w][SET][g][4*lg+r][16+lr] = __float2bfloat16(p1);
        rs[g][r] += p0 + p1;
      }
    }
    #pragma unroll
    for (int g=0; g<2; g++){
      bf16x8 bp = *(const bf16x8*)&pl[w][SET][g][lr][lg*8];
      facc[g][0] = __builtin_amdgcn_mfma_f32_16x16x32_bf16(V0, bp, facc[g][0], 0,0,0);
      facc[g][1] = __builtin_amdgcn_mfma_f32_16x16x32_bf16(V1, bp, facc[g][1], 0,0,0);
      facc[g][2] = __builtin_amdgcn_mfma_f32_16x16x32_bf16(V2, bp, facc[g][2], 0,0,0);
      facc[g][3] = __builtin_amdgcn_mfma_f32_16x16x32_bf16(V3, bp, facc[g][3], 0,0,0);
    }
  };

  bf16x8 kA0,kA1,kA2,kA3,vA0,vA1,vA2,vA3;
  bf16x8 kB0,kB1,kB2,kB3,vB0,vB1,vB2,vB3;
  #define FLOAD(KP,VP,J0) \
    KP##0 = *(const bf16x8*)(kbase + (size_t)(J0)*64); \
    KP##1 = *(const bf16x8*)(kbase + (size_t)(J0)*64 + 32); \
    KP##2 = *(const bf16x8*)(kbase + (size_t)(J0)*64 + 1024); \
    KP##3 = *(const bf16x8*)(kbase + (size_t)(J0)*64 + 1056); \
    VP##0 = *(const bf16x8*)(vbase + (J0)); \
    VP##1 = *(const bf16x8*)(vbase + 16*NM + (J0)); \
    VP##2 = *(const bf16x8*)(vbase + 32*NM + (J0)); \
    VP##3 = *(const bf16x8*)(vbase + 48*NM + (J0));

  FLOAD(kA,vA,0)
  for (int jt=0; jt<16; jt+=2){
    FLOAD(kB,vB,(jt+1)*32)
    fcomp(kA0,kA1,kA2,kA3,vA0,vA1,vA2,vA3,0);
    if (jt+2 < 16){ FLOAD(kA,vA,(jt+2)*32) }
    fcomp(kB0,kB1,kB2,kB3,vB0,vB1,vB2,vB3,1);
  }
  #undef FLOAD

  #pragma unroll
  for (int g=0; g<2; g++)
    #pragma unroll
    for (int r=0;r<4;r++){
      float v = rs[g][r];
      v += __shfl_xor(v,1); v += __shfl_xor(v,2); v += __shfl_xor(v,4); v += __shfl_xor(v,8);
      if (lr==0) rsl[w][g*16 + 4*lg+r] = v;
    }
  __syncthreads();
  #pragma unroll
  for (int g=0; g<2; g++){
    float inv = 1.f / rsl[w][g*16 + lr];
    #pragma unroll
    for (int dt=0; dt<4; dt++){
      #pragma unroll
      for (int r=0;r<4;r++){
        int d = dt*16 + 4*lg + r;
        fo[((size_t)(b*256 + d*4 + h))*NF + i0 + g*16 + lr] = facc[g][dt][r]*inv;
      }
    }
  }
}

// ---------------- map-direction attention partials (27 i-chunks of 16 tiles) ----
__global__ __launch_bounds__(256) void k_mattn(const __hip_bfloat16* __restrict__ qm,
    const __hip_bfloat16* __restrict__ qf, const __hip_bfloat16* __restrict__ vf,
    float* __restrict__ num, float* __restrict__ cs){
  int ic = blockIdx.x, jb = blockIdx.y, bh = blockIdx.z;
  int w = threadIdx.x>>6, l = threadIdx.x&63;
  int lr = l&15, lg = l>>4;
  int jt0 = jb*64 + w*16;
  __shared__ __hip_bfloat16 pl[4][2][16][40];
  const __hip_bfloat16* ab = qm + ((size_t)bh*NM + jt0 + lr)*64 + lg*8;
  bf16x8 am0 = *(const bf16x8*)(ab);
  bf16x8 am1 = *(const bf16x8*)(ab + 32);
  f32x4 macc[4];
  #pragma unroll
  for (int t=0;t<4;t++){ macc[t][0]=0.f; macc[t][1]=0.f; macc[t][2]=0.f; macc[t][3]=0.f; }
  float csr[4] = {0.f,0.f,0.f,0.f};
  const __hip_bfloat16* fbase  = qf + ((size_t)bh*NF + lr)*64 + lg*8;
  const __hip_bfloat16* vfbase = vf + ((size_t)bh*64 + lr)*NF + lg*8;

  auto mcomp = [&](bf16x8 F0, bf16x8 F1, bf16x8 F2, bf16x8 F3,
                   bf16x8 V0, bf16x8 V1, bf16x8 V2, bf16x8 V3, int SET){
    f32x4 s0 = {0.f,0.f,0.f,0.f}, s1 = {0.f,0.f,0.f,0.f};
    s0 = __builtin_amdgcn_mfma_f32_16x16x32_bf16(am0, F0, s0, 0,0,0);
    s0 = __builtin_amdgcn_mfma_f32_16x16x32_bf16(am1, F1, s0, 0,0,0);
    s1 = __builtin_amdgcn_mfma_f32_16x16x32_bf16(am0, F2, s1, 0,0,0);
    s1 = __builtin_amdgcn_mfma_f32_16x16x32_bf16(am1, F3, s1, 0,0,0);
    #pragma unroll
    for (int r=0;r<4;r++){
      float p0 = __expf(s0[r]*0.125f);
      float p1 = __expf(s1[r]*0.125f);
      pl[w][SET][4*lg+r][lr]    = __float2bfloat16(p0);
      pl[w][SET][4*lg+r][16+lr] = __float2bfloat16(p1);
      csr[r] += p0 + p1;
    }
    bf16x8 bp = *(const bf16x8*)&pl[w][SET][lr][lg*8];
    macc[0] = __builtin_amdgcn_mfma_f32_16x16x32_bf16(V0, bp, macc[0], 0,0,0);
    macc[1] = __builtin_amdgcn_mfma_f32_16x16x32_bf16(V1, bp, macc[1], 0,0,0);
    macc[2] = __builtin_amdgcn_mfma_f32_16x16x32_bf16(V2, bp, macc[2], 0,0,0);
    macc[3] = __builtin_amdgcn_mfma_f32_16x16x32_bf16(V3, bp, macc[3], 0,0,0);
  };

  bf16x8 fA0,fA1,fA2,fA3,vA0,vA1,vA2,vA3;
  bf16x8 fB0,fB1,fB2,fB3,vB0,vB1,vB2,vB3;
  #define MLOAD(FP,VP,I0) \
    FP##0 = *(const bf16x8*)(fbase + (size_t)(I0)*64); \
    FP##1 = *(const bf16x8*)(fbase + (size_t)(I0)*64 + 32); \
    FP##2 = *(const bf16x8*)(fbase + (size_t)(I0)*64 + 1024); \
    FP##3 = *(const bf16x8*)(fbase + (size_t)(I0)*64 + 1056); \
    VP##0 = *(const bf16x8*)(vfbase + (size_t)(I0)); \
    VP##1 = *(const bf16x8*)(vfbase + (size_t)16*NF + (I0)); \
    VP##2 = *(const bf16x8*)(vfbase + (size_t)32*NF + (I0)); \
    VP##3 = *(const bf16x8*)(vfbase + (size_t)48*NF + (I0));

  int ibase = ic*512;
  MLOAD(fA,vA, ibase)
  for (int is=0; is<16; is+=2){
    MLOAD(fB,vB, ibase + (is+1)*32)
    mcomp(fA0,fA1,fA2,fA3,vA0,vA1,vA2,vA3,0);
    if (is+2<16){ MLOAD(fA,vA, ibase + (is+2)*32) }
    mcomp(fB0,fB1,fB2,fB3,vB0,vB1,vB2,vB3,1);
  }
  #undef MLOAD

  size_t nb = ((size_t)(ic*8 + bh)*64)*512;
  #pragma unroll
  for (int dt=0;dt<4;dt++){
    #pragma unroll
    for (int r=0;r<4;r++){
      num[nb + (size_t)(dt*16 + 4*lg + r)*512 + jt0 + lr] = macc[dt][r];
    }
  }
  #pragma unroll
  for (int r=0;r<4;r++){
    float v = csr[r];
    v += __shfl_xor(v,1); v += __shfl_xor(v,2); v += __shfl_xor(v,4); v += __shfl_xor(v,8);
    if (lr==0) cs[(size_t)(ic*8 + bh)*512 + jt0 + 4*lg + r] = v;
  }
}

// ---------------- combine map-dir partials -> ma merged-channel layout ----------------
__global__ void k_comb(const float* __restrict__ num, const float* __restrict__ cs,
                       float* __restrict__ ma){
  int idx = blockIdx.x*256 + threadIdx.x;
  if (idx >= 8*512*64) return;
  int bh = idx>>15; int rem = idx&32767; int j = rem>>6; int d = rem&63;
  float s=0.f, c=0.f;
  for (int ic=0;ic<NIC;ic++){
    s += num[((size_t)(ic*8+bh)*64 + d)*512 + j];
    c += cs[(size_t)(ic*8+bh)*512 + j];
  }
  int b = bh>>2, h = bh&3;
  ma[((size_t)(b*256 + d*4 + h))*NM + j] = s/c;
}

// ---------------- squeeze-excite MLP (tiny) ----------------
__global__ void k_se(const float2* __restrict__ st, const float* __restrict__ w1, const float* __restrict__ b1,
                     const float* __restrict__ w2, const float* __restrict__ b2, float* __restrict__ sout){
  int b = blockIdx.x; int t = threadIdx.x;
  __shared__ float mean[512]; __shared__ float s1[128];
  mean[t]     = st[b*512 + t].x;
  mean[t+256] = st[b*512 + t + 256].x;
  __syncthreads();
  if (t<128){
    float a = b1[t];
    for (int c=0;c<512;c++) a += w1[t*512+c]*mean[c];
    s1[t] = fmaxf(a, 0.f);
  }
  __syncthreads();
  for (int o=t;o<512;o+=256){
    float a = b2[o];
    for (int c=0;c<128;c++) a += w2[o*128+c]*s1[c];
    sout[b*512+o] = 1.f/(1.f+__expf(-a));
  }
}

extern "C" void kernel_launch(void* const* d_in, const int* in_sizes, int n_in,
                              void* d_out, int out_size, void* d_ws, size_t ws_size,
                              hipStream_t stream){
  const float* x     = (const float*)d_in[0];
  const float* smap  = (const float*)d_in[1];
  const float* wfdw  = (const float*)d_in[2];
  const float* wfpw  = (const float*)d_in[3];
  const float* wmqv  = (const float*)d_in[4];
  const float* wodw  = (const float*)d_in[5];
  const float* wopw  = (const float*)d_in[6];
  const float* wmout = (const float*)d_in[7];
  const float* wexp  = (const float*)d_in[8];
  const float* wdw   = (const float*)d_in[9];
  const float* wse1  = (const float*)d_in[10];
  const float* bse1  = (const float*)d_in[11];
  const float* wse2  = (const float*)d_in[12];
  const float* bse2  = (const float*)d_in[13];
  const float* wpw   = (const float*)d_in[14];

  float* out  = (float*)d_out;                        // [2][128][NF]
  float* mout = out + (size_t)2*128*NF;               // [2][128][NM]

  float* W = (float*)d_ws;
  size_t o = 0;
  __hip_bfloat16* qf = (__hip_bfloat16*)(W + o); o += (size_t)8*NF*32;   // bf16 [8][NF][64]
  __hip_bfloat16* vf = (__hip_bfloat16*)(W + o); o += (size_t)8*NF*32;   // bf16 [8][64][NF]
  float* fdw  = W + o; o += (size_t)2*128*NF;
  float* num  = W + o; o += (size_t)NIC*8*64*512;
  __hip_bfloat16* qm = (__hip_bfloat16*)(W + o); o += 8*NM*32;           // bf16 [8][512][64]
  __hip_bfloat16* vm = (__hip_bfloat16*)(W + o); o += 8*NM*32;           // bf16 [8][64][512]
  float* csb  = W + o; o += (size_t)NIC*8*512;
  float* ma   = W + o; o += (size_t)2*256*NM;
  float* h2   = (float*)d_ws;
  float* fo   = W + o; o += (size_t)2*256*NF;
  float* fdw2 = W + o; o += (size_t)2*256*NF;
  float* h1 = fo;
  float* wTf  = W + o; o += 512*128;
  float* wTm  = W + o; o += 512*128;
  float* wTo  = W + o; o += 128*256;
  float* wTmo = W + o; o += 128*256;
  float* wTe  = W + o; o += 512*128;
  float* wTp  = W + o; o += 128*512;
  float2* stA = (float2*)(W+o); o += 512;
  float2* tfA = (float2*)(W+o); o += 512;
  float2* stM = (float2*)(W+o); o += 512;
  float2* tfM = (float2*)(W+o); o += 512;
  float2* stO = (float2*)(W+o); o += 512;
  float2* tfO = (float2*)(W+o); o += 512;
  float2* stH1= (float2*)(W+o); o += 2048;
  float2* tfH1= (float2*)(W+o); o += 2048;
  float2* stH2= (float2*)(W+o); o += 2048;
  float2* tfH = (float2*)(W+o); o += 2048;
  float* sbuf = W + o; o += 1024;
  (void)ws_size; (void)in_sizes; (void)n_in; (void)out_size;

  // merged weight transposes
  k_transpose6<<<dim3(256,6),256,0,stream>>>(wfpw,wTf, wmqv,wTm, wopw,wTo, wmout,wTmo, wexp,wTe, wpw,wTp);

  // feat path
  k_stats<<<256,256,0,stream>>>(x, stA, NF, tfA);
  k_dw3t<<<256,256,0,stream>>>(x, wfdw, tfA, fdw, 128, 0);
  k_pw<<<dim3(216,8,2),256,0,stream>>>(fdw, wTf, nullptr,0, 128,512,NF, nullptr, nullptr, qf, vf, 1);

  // map path
  k_stats<<<256,256,0,stream>>>(smap, stM, NM, tfM);
  k_pw<<<dim3(8,8,2),256,0,stream>>>(smap, wTm, tfM,0, 128,512,NM, nullptr, nullptr, qm, vm, 1);

  // attention, both directions (MFMA)
  k_fattn<<<dim3(108,8),256,0,stream>>>(qf, qm, vm, fo);
  k_mattn<<<dim3(NIC,8,8),256,0,stream>>>(qm, qf, vf, num, csb);
  k_comb<<<1024,256,0,stream>>>(num, csb, ma);

  // output convs + residuals
  k_dw3t<<<512,256,0,stream>>>(fo, wodw, nullptr, fdw2, 256, 0);
  k_pw<<<dim3(216,2,2),256,0,stream>>>(fdw2, wTo, nullptr,0, 256,128,NF, x, out, nullptr,nullptr, 0);
  k_pw<<<dim3(8,2,2),256,0,stream>>>(ma, wTmo, nullptr,0, 256,128,NM, smap, mout, nullptr,nullptr, 0);

  // MBConv
  k_stats<<<256,256,0,stream>>>(out, stO, NF, tfO);
  k_pw<<<dim3(216,8,2),256,0,stream>>>(out, wTe, tfO,1, 128,512,NF, nullptr, h1, nullptr,nullptr, 0);

  k_stats<<<1024,256,0,stream>>>(h1, stH1, NF, tfH1);
  k_dw3t<<<1024,256,0,stream>>>(h1, wdw, tfH1, h2, 512, 1);

  k_stats<<<1024,256,0,stream>>>(h2, stH2, NF, nullptr);
  k_se<<<2,256,0,stream>>>(stH2, wse1,bse1,wse2,bse2, sbuf);
  k_make_tf<<<4,256,0,stream>>>(stH2, sbuf, tfH, 1024);
  k_pw<<<dim3(216,2,2),256,0,stream>>>(h2, wTp, tfH,0, 512,128,NF, out, out, nullptr,nullptr, 0);
}